// Round 5
// baseline (591.310 us; speedup 1.0000x reference)
//
#include <hip/hip_runtime.h>
#include <math.h>

#define SEQL 784
#define HIDN 512
#define OUTD 10

typedef float v2 __attribute__((ext_vector_type(2)));

// DPP mov: lanes not selected by row_mask, or with invalid source (bound_ctrl),
// yield 0. Single-use results are foldable into v_{add,fmac}_f32_dpp.
template<int CTRL, int RM>
__device__ __forceinline__ float dpp0(float v) {
    int r = __builtin_amdgcn_update_dpp(0, __builtin_bit_cast(int, v),
                                        CTRL, RM, 0xF, true);
    return __builtin_bit_cast(float, r);
}
__device__ __forceinline__ v2 sp(float v) { v2 r; r.x = v; r.y = v; return r; }
__device__ __forceinline__ v2 vfma(v2 a, v2 b, v2 c) {
    return __builtin_elementwise_fma(a, b, c);   // -> v_pk_fma_f32
}

// M[i][o] = sum_j C1[j][i] * W[j][o]  (512 x 10): logits = h2f @ M + b.
__global__ __launch_bounds__(256) void compute_M(const float* __restrict__ C1,
                                                 const float* __restrict__ W,
                                                 float* __restrict__ M) {
    __shared__ float Ws[HIDN * OUTD];
    __shared__ float red[4][64][OUTD];
    const int lane = threadIdx.x & 63, w = threadIdx.x >> 6;
    const int i = blockIdx.x * 64 + lane;
    for (int idx = threadIdx.x; idx < HIDN * OUTD; idx += 256) Ws[idx] = W[idx];
    __syncthreads();
    float acc[OUTD];
#pragma unroll
    for (int o = 0; o < OUTD; ++o) acc[o] = 0.f;
    for (int j = w * 128; j < w * 128 + 128; ++j) {
        float cv = C1[j * HIDN + i];
#pragma unroll
        for (int o = 0; o < OUTD; ++o) acc[o] = fmaf(cv, Ws[j * OUTD + o], acc[o]);
    }
#pragma unroll
    for (int o = 0; o < OUTD; ++o) red[w][lane][o] = acc[o];
    __syncthreads();
    if (w == 0) {
#pragma unroll
        for (int o = 0; o < OUTD; ++o)
            M[i * OUTD + o] = (red[0][lane][o] + red[1][lane][o]) +
                              (red[2][lane][o] + red[3][lane][o]);
    }
}

// TWO waves per batch row (4 hidden elems/lane), 2 rows per 256-thread block,
// grid 512 -> 2 independent blocks/CU (barrier stalls of one block hide under
// the other). Per step: per-wave DPP affine scan; lo-wave publishes its wave
// total (r,s); one __syncthreads; hi-wave composes via precomputed (Ain,Bin);
// y0 crosses waves as 2 partial sums. Parity double-buffered LDS slots make a
// single barrier per step race-free.
__global__ __launch_bounds__(256, 2) void ssm_main(const float* __restrict__ x,
                                                   const float* __restrict__ C0,
                                                   const float* __restrict__ Mmat,
                                                   const float* __restrict__ bias,
                                                   float* __restrict__ out) {
    const int tid = threadIdx.x;
    const int wave = tid >> 6;
    const int lane = tid & 63;
    const int rowl = wave >> 1;      // row within block (0..1)
    const int half = wave & 1;       // which half of the hidden dim
    const int row = blockIdx.x * 2 + rowl;

    __shared__ float xs[2][SEQL + 2];
    __shared__ float tot[2][2][2][4];   // [parity][rowl][half][rx,ry,sx,sy]; half=0 slot stays 0
    __shared__ float y0p[2][2][2];      // [parity][rowl][half] partial dots
    __shared__ double bdB[2];           // setup handoff (Bd solve)
    __shared__ float red[2][2][OUTD];
    __shared__ float Ms[HIDN * OUTD];

    const float DEL = 1.0f / 784.0f;
    for (int idx = tid; idx < 2 * SEQL; idx += 256)
        xs[idx / SEQL][idx % SEQL] = DEL * x[blockIdx.x * 2 * SEQL + idx];
    if (tid < 4) xs[tid >> 1][SEQL + (tid & 1)] = 0.f;
    if (tid < 32) ((float*)tot)[tid] = 0.f;
    if (tid < 8) ((float*)y0p)[tid] = 0.f;

    // ---- per-lane constants (fp64 -> fp32, matching reference f64 A_d/B_d)
    const double cd = 1.0 / 1568.0;            // step/2
    const double F = 2.0 * 1.4426950408889634; // 2*log2(e) fold for exp2
    float P[4], Ps[4], a_[4], G2[4], mE2[4], K1[4], K2[4], Bd2[4], C0d[4];
    double apD = 0.0, bpD = 1.0;               // in-lane partial (alpha, beta)
    double aL = 1.0, bL = 0.0;                 // lane-local Bd-solve affine
#pragma unroll
    for (int j = 0; j < 4; ++j) {
        int i = half * 256 + lane * 4 + j;
        double Pd = sqrt(1.0 + 2.0 * (double)i);
        double dd = 1.0 + cd * (double)(i + 1);
        double fd = 1.0 / dd;
        double ad = (1.0 - cd * (double)i) * fd;
        double mEd = -cd * Pd * fd;
        double ed = Pd * mEd;                   // -cP^2/d
        double Gd = (1.0 - cd * (double)(i + 1)) * fd;
        K2[j] = (float)(F * mEd * (1.0 + apD));
        K1[j] = (float)(F * mEd * bpD);
        apD = ad * apD + ed;
        bpD = ad * bpD;
        P[j]   = (float)Pd;
        Ps[j]  = (float)(Pd / F);
        a_[j]  = (float)ad;
        G2[j]  = (float)(F * Gd);
        mE2[j] = (float)(F * mEd);
        C0d[j] = DEL * C0[i];
        bL = ad * bL + Pd * Pd * fd;
        aL *= ad;
    }
    // ---- scan-level constants mirroring the DPP segment structure (per wave)
    float ac[6], bc[6];
    {
        double al = apD, be = bpD;
        int rl = lane & 15;
#pragma unroll
        for (int L = 0; L < 4; ++L) {          // row_shr:1,2,4,8 (row-capped)
            int d = 1 << L;
            ac[L] = (float)al; bc[L] = (float)be;
            double pa = __shfl_up(al, d, 64);
            double pb = __shfl_up(be, d, 64);
            if (rl >= d) { al += be * pa; be *= pb; }
        }
        ac[4] = (float)al; bc[4] = (float)be;  // row_bcast:15 -> rows 1,3
        {
            int src = (lane & 32) + 15;
            double pa = __shfl(al, src, 64);
            double pb = __shfl(be, src, 64);
            if (lane & 16) { al += be * pa; be *= pb; }
        }
        ac[5] = (float)al; bc[5] = (float)be;  // row_bcast:31 -> rows 2,3
        {
            double pa = __shfl(al, 31, 64);
            double pb = __shfl(be, 31, 64);
            if (lane >= 32) { al += be * pa; be *= pb; }
        }
    }
    // ---- (Ain,Bin): exclusive affine aggregate of THIS wave's lanes [0,lane)
    // s_in_global = si_local + Ain*rT + Bin*sT  (rT,sT = incoming wave totals)
    float Ain, Bin;
    {
        double A = apD, Bq = bpD;
#pragma unroll
        for (int d = 1; d < 64; d <<= 1) {
            double pa = __shfl_up(A, d, 64);
            double pb = __shfl_up(Bq, d, 64);
            if (lane >= d) { A = Bq * pa + A; Bq *= pb; }
        }
        double Ae = __shfl_up(A, 1, 64);
        double Be = __shfl_up(Bq, 1, 64);
        if (lane == 0) { Ae = 0.0; Be = 1.0; }
        Ain = (float)Ae; Bin = (float)Be;
    }
    // ---- Bd = (I - cA)^-1 P, fp64; cross-wave via LDS handoff of lo's total
    {
        double A = aL, B = bL;
#pragma unroll
        for (int d = 1; d < 64; d <<= 1) {
            double pA = __shfl_up(A, d, 64);
            double pB = __shfl_up(B, d, 64);
            if (lane >= d) { B = A * pB + B; A *= pA; }
        }
        double Aex = __shfl_up(A, 1, 64);
        double Bex = __shfl_up(B, 1, 64);
        if (lane == 0) { Aex = 1.0; Bex = 0.0; }
        if (half == 0 && lane == 63) bdB[rowl] = B;   // lo wave inclusive total
        __syncthreads();   // also covers xs/tot/y0p init
        double sIn = half ? bdB[rowl] : 0.0;
        double s = Aex * sIn + Bex;
#pragma unroll
        for (int j = 0; j < 4; ++j) {
            int i = half * 256 + lane * 4 + j;
            double Pd = sqrt(1.0 + 2.0 * (double)i);
            double fd = 1.0 / (1.0 + cd * (double)(i + 1));
            double ad = (1.0 - cd * (double)i) * fd;
            Bd2[j] = (float)(F * (Pd - cd * Pd * s) * fd);
            s = ad * s + Pd * Pd * fd;
        }
    }

    v2 h[4];
#pragma unroll
    for (int j = 0; j < 4; ++j) h[j] = sp(0.f);

    float u1 = xs[rowl][0];   // pre-scaled by DEL

    for (int k = 0; k < SEQL + 1; ++k) {
        const int p = k & 1, q = p ^ 1;
        float u_next = xs[rowl][k + 1];

        // ---- pass 1: per-lane local (r,s); store inner (scaled) and sb
        v2 inner[4], sb[4];
        v2 r = sp(0.f), s = sp(0.f);
#pragma unroll
        for (int j = 0; j < 4; ++j) {
            v2 hj = h[j];
            v2 in_ = vfma(sp(mE2[j]), r, sp(G2[j]) * hj);
            inner[j] = in_;
            sb[j] = s;
            s = vfma(sp(a_[j]), s, sp(Ps[j]) * in_);
            r = vfma(sp(P[j]), hj, r);
        }

        // ---- per-wave affine scan via DPP (single-use, foldable)
#define LVL(CTRL, RM, L) {                                                   \
        s.x = fmaf(bc[L], dpp0<CTRL, RM>(s.x),                               \
                   fmaf(ac[L], dpp0<CTRL, RM>(r.x), s.x));                   \
        s.y = fmaf(bc[L], dpp0<CTRL, RM>(s.y),                               \
                   fmaf(ac[L], dpp0<CTRL, RM>(r.y), s.y));                   \
        r.x += dpp0<CTRL, RM>(r.x);                                          \
        r.y += dpp0<CTRL, RM>(r.y); }
        LVL(0x111, 0xF, 0)   // row_shr:1
        LVL(0x112, 0xF, 1)   // row_shr:2
        LVL(0x114, 0xF, 2)   // row_shr:4
        LVL(0x118, 0xF, 3)   // row_shr:8
        LVL(0x142, 0xA, 4)   // row_bcast:15 -> rows 1,3
        LVL(0x143, 0xC, 5)   // row_bcast:31 -> rows 2,3
#undef LVL
        v2 ri, si;           // exclusive local (lane0 = 0)
        ri.x = dpp0<0x138, 0xF>(r.x);  ri.y = dpp0<0x138, 0xF>(r.y);
        si.x = dpp0<0x138, 0xF>(s.x);  si.y = dpp0<0x138, 0xF>(s.y);

        // lo publishes its wave-inclusive totals (lane 63) for hi to compose
        if (half == 0 && lane == 63) {
            tot[p][rowl][1][0] = r.x; tot[p][rowl][1][1] = r.y;
            tot[p][rowl][1][2] = s.x; tot[p][rowl][1][3] = s.y;
        }
        __syncthreads();

        v2 rT, sT;
        rT.x = tot[p][rowl][half][0]; rT.y = tot[p][rowl][half][1];
        sT.x = tot[p][rowl][half][2]; sT.y = tot[p][rowl][half][3];
        float y0s = y0p[q][rowl][0] + y0p[q][rowl][1];
        v2 du; du.x = u1; du.y = y0s;
        v2 rig = ri + rT;
        v2 sig = vfma(sp(Bin), sT, vfma(sp(Ain), rT, si));

        // ---- pass 2: yy = inner + mE2*sb + K2*rig + K1*sig + Bd2*du, tanh
        float part = 0.f;
#pragma unroll
        for (int j = 0; j < 4; ++j) {
            v2 yy = vfma(sp(mE2[j]), sb[j], inner[j]);
            yy = vfma(sp(K2[j]), rig, yy);
            yy = vfma(sp(K1[j]), sig, yy);
            yy = vfma(sp(Bd2[j]), du, yy);
            v2 e;  e.x = __builtin_amdgcn_exp2f(yy.x);
                   e.y = __builtin_amdgcn_exp2f(yy.y);
            v2 e1 = e + sp(1.f);
            v2 rc; rc.x = __builtin_amdgcn_rcpf(e1.x);
                   rc.y = __builtin_amdgcn_rcpf(e1.y);
            v2 hn = vfma(sp(-2.f), rc, sp(1.f));
            h[j] = hn;
            part = fmaf(C0d[j], hn.x, part);
        }
        // y0 partial (this wave's 256 elems): DPP reduce -> lane 63 -> LDS
        part += dpp0<0x111, 0xF>(part);
        part += dpp0<0x112, 0xF>(part);
        part += dpp0<0x114, 0xF>(part);
        part += dpp0<0x118, 0xF>(part);
        part += dpp0<0x142, 0xA>(part);
        part += dpp0<0x143, 0xC>(part);
        if (lane == 63) y0p[p][rowl][half] = part;
        u1 = u_next;
    }

    // ---- epilogue: logits[row] = h2_final @ M + b (cross-wave via LDS)
    __syncthreads();
    for (int idx = tid; idx < HIDN * OUTD; idx += 256) Ms[idx] = Mmat[idx];
    __syncthreads();

    float acc[OUTD];
#pragma unroll
    for (int o = 0; o < OUTD; ++o) acc[o] = 0.f;
#pragma unroll
    for (int j = 0; j < 4; ++j) {
        float hv = h[j].y;
        int i = half * 256 + lane * 4 + j;
#pragma unroll
        for (int o = 0; o < OUTD; ++o) acc[o] = fmaf(hv, Ms[i * OUTD + o], acc[o]);
    }
#pragma unroll
    for (int o = 0; o < OUTD; ++o) {
#pragma unroll
        for (int d = 32; d; d >>= 1) acc[o] += __shfl_xor(acc[o], d, 64);
    }
    if (lane == 0) {
#pragma unroll
        for (int o = 0; o < OUTD; ++o) red[rowl][half][o] = acc[o];
    }
    __syncthreads();
    if (half == 0 && lane == 0) {
#pragma unroll
        for (int o = 0; o < OUTD; ++o)
            out[row * OUTD + o] = red[rowl][0][o] + red[rowl][1][o] + bias[o];
    }
}

extern "C" void kernel_launch(void* const* d_in, const int* in_sizes, int n_in,
                              void* d_out, int out_size, void* d_ws, size_t ws_size,
                              hipStream_t stream) {
    const float* x  = (const float*)d_in[0];  // (1024, 784)
    const float* C0 = (const float*)d_in[1];  // (1, 512)
    const float* C1 = (const float*)d_in[2];  // (512, 512)
    const float* W  = (const float*)d_in[3];  // (512, 10)
    const float* b  = (const float*)d_in[4];  // (10,)
    float* M = (float*)d_ws;                  // 512*10 fp32 scratch

    compute_M<<<dim3(8), dim3(256), 0, stream>>>(C1, W, M);
    ssm_main<<<dim3(512), dim3(256), 0, stream>>>(x, C0, M, b, (float*)d_out);
}

// Round 6
// 567.537 us; speedup vs baseline: 1.0419x; 1.0419x over previous
//
#include <hip/hip_runtime.h>
#include <math.h>

#define SEQL 784
#define HIDN 512
#define OUTD 10

// DPP mov: lanes not selected by row_mask, or with invalid source (bound_ctrl),
// yield 0. Single-use results are foldable into v_{add,fmac}_f32_dpp.
template<int CTRL, int RM>
__device__ __forceinline__ float dpp0(float v) {
    int r = __builtin_amdgcn_update_dpp(0, __builtin_bit_cast(int, v),
                                        CTRL, RM, 0xF, true);
    return __builtin_bit_cast(float, r);
}

// M[i][o] = sum_j C1[j][i] * W[j][o]  (512 x 10): logits = h2f @ M + b.
__global__ __launch_bounds__(256) void compute_M(const float* __restrict__ C1,
                                                 const float* __restrict__ W,
                                                 float* __restrict__ M) {
    __shared__ float Ws[HIDN * OUTD];
    __shared__ float red[4][64][OUTD];
    const int lane = threadIdx.x & 63, w = threadIdx.x >> 6;
    const int i = blockIdx.x * 64 + lane;
    for (int idx = threadIdx.x; idx < HIDN * OUTD; idx += 256) Ws[idx] = W[idx];
    __syncthreads();
    float acc[OUTD];
#pragma unroll
    for (int o = 0; o < OUTD; ++o) acc[o] = 0.f;
    for (int j = w * 128; j < w * 128 + 128; ++j) {
        float cv = C1[j * HIDN + i];
#pragma unroll
        for (int o = 0; o < OUTD; ++o) acc[o] = fmaf(cv, Ws[j * OUTD + o], acc[o]);
    }
#pragma unroll
    for (int o = 0; o < OUTD; ++o) red[w][lane][o] = acc[o];
    __syncthreads();
    if (w == 0) {
#pragma unroll
        for (int o = 0; o < OUTD; ++o)
            M[i * OUTD + o] = (red[0][lane][o] + red[1][lane][o]) +
                              (red[2][lane][o] + red[3][lane][o]);
    }
}

// LAYER-split: one block (128 thr = 2 waves) per batch row. wave0 = layer 1,
// wave1 = layer 2 (lags one step). Each wave owns its layer's full 512 hidden
// elems (8/lane, scalar fp32) and runs the SAME one-affine-scan step as R4:
//   h <- tanh(solve((I+cA)h) + du*Bd),  scan state (r = prefix P.h, s).
// Coupling is ONE scalar y0 with a full step of slack: wave1 reads the
// previous step's value at loop top (needed only in pass 2), wave0 writes at
// loop bottom; parity double-buffer + one end-of-step barrier -> no mid-step
// dependency. 2048 waves = 2 waves/SIMD so one wave's quarter-rate exp2/rcp
// occupancy hides under the other wave's VALU issue.
__global__ __launch_bounds__(128, 2) void ssm_main(const float* __restrict__ x,
                                                   const float* __restrict__ C0,
                                                   const float* __restrict__ Mmat,
                                                   const float* __restrict__ bias,
                                                   float* __restrict__ out) {
    const int tid = threadIdx.x;
    const int wave = tid >> 6;      // 0 = layer 1, 1 = layer 2
    const int lane = tid & 63;
    const int row = blockIdx.x;

    __shared__ float xs[SEQL + 2];
    __shared__ float y0buf[2];      // parity slots for DEL*(C0 . h1)

    const float DEL = 1.0f / 784.0f;
    for (int idx = tid; idx < SEQL; idx += 128)
        xs[idx] = DEL * x[row * SEQL + idx];
    if (tid < 2) { xs[SEQL + tid] = 0.f; y0buf[tid] = 0.f; }

    // ---- per-lane constants (fp64 -> fp32, matching reference f64 A_d/B_d)
    const double cd = 1.0 / 1568.0;            // step/2
    const double F = 2.0 * 1.4426950408889634; // 2*log2(e) fold for exp2
    float P[8], Ps[8], a_[8], G2[8], mE2[8], K1[8], K2[8], Bd2[8], C0d[8];
    double apD = 0.0, bpD = 1.0;               // in-lane partial (alpha, beta)
    double aL = 1.0, bL = 0.0;                 // lane-local Bd-solve affine
#pragma unroll
    for (int j = 0; j < 8; ++j) {
        int i = lane * 8 + j;
        double Pd = sqrt(1.0 + 2.0 * (double)i);
        double dd = 1.0 + cd * (double)(i + 1);
        double fd = 1.0 / dd;
        double ad = (1.0 - cd * (double)i) * fd;
        double mEd = -cd * Pd * fd;
        double ed = Pd * mEd;                   // -cP^2/d
        double Gd = (1.0 - cd * (double)(i + 1)) * fd;
        K2[j] = (float)(F * mEd * (1.0 + apD));
        K1[j] = (float)(F * mEd * bpD);
        apD = ad * apD + ed;
        bpD = ad * bpD;
        P[j]   = (float)Pd;
        Ps[j]  = (float)(Pd / F);
        a_[j]  = (float)ad;
        G2[j]  = (float)(F * Gd);
        mE2[j] = (float)(F * mEd);
        C0d[j] = DEL * C0[i];
        bL = ad * bL + Pd * Pd * fd;
        aL *= ad;
    }
    // ---- scan-level constants mirroring the DPP segment structure
    float ac[6], bc[6];
    {
        double al = apD, be = bpD;
        int rl = lane & 15;
#pragma unroll
        for (int L = 0; L < 4; ++L) {          // row_shr:1,2,4,8 (row-capped)
            int d = 1 << L;
            ac[L] = (float)al; bc[L] = (float)be;
            double pa = __shfl_up(al, d, 64);
            double pb = __shfl_up(be, d, 64);
            if (rl >= d) { al += be * pa; be *= pb; }
        }
        ac[4] = (float)al; bc[4] = (float)be;  // row_bcast:15 -> rows 1,3
        {
            int src = (lane & 32) + 15;
            double pa = __shfl(al, src, 64);
            double pb = __shfl(be, src, 64);
            if (lane & 16) { al += be * pa; be *= pb; }
        }
        ac[5] = (float)al; bc[5] = (float)be;  // row_bcast:31 -> rows 2,3
        {
            double pa = __shfl(al, 31, 64);
            double pb = __shfl(be, 31, 64);
            if (lane >= 32) { al += be * pa; be *= pb; }
        }
    }
    // ---- Bd = (I - cA)^-1 P, solved once in fp64 (wave affine scan)
    {
        double A = aL, B = bL;
#pragma unroll
        for (int d = 1; d < 64; d <<= 1) {
            double pA = __shfl_up(A, d, 64);
            double pB = __shfl_up(B, d, 64);
            if (lane >= d) { B = A * pB + B; A *= pA; }
        }
        double sIn = __shfl_up(B, 1, 64);
        double s = lane ? sIn : 0.0;
#pragma unroll
        for (int j = 0; j < 8; ++j) {
            int i = lane * 8 + j;
            double Pd = sqrt(1.0 + 2.0 * (double)i);
            double fd = 1.0 / (1.0 + cd * (double)(i + 1));
            double ad = (1.0 - cd * (double)i) * fd;
            Bd2[j] = (float)(F * (Pd - cd * Pd * s) * fd);
            s = ad * s + Pd * Pd * fd;
        }
    }
    __syncthreads();   // xs / y0buf init visible to both waves

    float h[8];
#pragma unroll
    for (int j = 0; j < 8; ++j) h[j] = 0.f;

    float u1 = xs[0];   // pre-scaled by DEL (wave0's step-0 input)

#pragma unroll 2
    for (int k = 0; k < SEQL + 1; ++k) {
        const int p = k & 1, q = p ^ 1;
        // wave1's input: previous step's y0 (slack until pass 2).
        // wave0's input: u1. (LDS read issued for both; trivial.)
        float yprev = y0buf[q];
        float du = wave ? yprev : u1;
        float u_next = xs[k + 1];

        // ---- pass 1: per-lane local (r,s); store inner (scaled) and sb
        float inner[8], sb[8];
        float r = 0.f, s = 0.f;
#pragma unroll
        for (int j = 0; j < 8; ++j) {
            float hj = h[j];
            float in_ = fmaf(mE2[j], r, G2[j] * hj);
            inner[j] = in_;
            sb[j] = s;
            s = fmaf(a_[j], s, Ps[j] * in_);
            r = fmaf(P[j], hj, r);
        }

        // ---- wave affine scan via DPP (single-use, foldable)
#define LVL(CTRL, RM, L) {                                                   \
        s = fmaf(bc[L], dpp0<CTRL, RM>(s),                                   \
                 fmaf(ac[L], dpp0<CTRL, RM>(r), s));                         \
        r += dpp0<CTRL, RM>(r); }
        LVL(0x111, 0xF, 0)   // row_shr:1
        LVL(0x112, 0xF, 1)   // row_shr:2
        LVL(0x114, 0xF, 2)   // row_shr:4
        LVL(0x118, 0xF, 3)   // row_shr:8
        LVL(0x142, 0xA, 4)   // row_bcast:15 -> rows 1,3
        LVL(0x143, 0xC, 5)   // row_bcast:31 -> rows 2,3
#undef LVL
        float ri = dpp0<0x138, 0xF>(r);   // wave_shr:1 -> exclusive (lane0=0)
        float si = dpp0<0x138, 0xF>(s);

        // ---- pass 2: yy = inner + mE2*sb + K2*ri + K1*si + Bd2*du, tanh
        float part = 0.f;
#pragma unroll
        for (int j = 0; j < 8; ++j) {
            float yy = fmaf(mE2[j], sb[j], inner[j]);
            yy = fmaf(K2[j], ri, yy);
            yy = fmaf(K1[j], si, yy);
            yy = fmaf(Bd2[j], du, yy);
            float e = __builtin_amdgcn_exp2f(yy);
            float rc = __builtin_amdgcn_rcpf(e + 1.f);
            float hn = fmaf(-2.f, rc, 1.f);
            h[j] = hn;
            part = fmaf(C0d[j], hn, part);   // dead for wave1 (C0d unused ok)
        }
        // wave0 publishes y0 = DEL*(C0 . h1_new) for wave1's NEXT step
        if (wave == 0) {
            part += dpp0<0x111, 0xF>(part);
            part += dpp0<0x112, 0xF>(part);
            part += dpp0<0x114, 0xF>(part);
            part += dpp0<0x118, 0xF>(part);
            part += dpp0<0x142, 0xA>(part);
            part += dpp0<0x143, 0xC>(part);
            if (lane == 63) y0buf[p] = part;
        }
        __syncthreads();
        u1 = u_next;
    }

    // ---- epilogue: wave1 owns h2_final; logits = h2 @ M + b (M from global)
    if (wave == 1) {
        float acc[OUTD];
#pragma unroll
        for (int o = 0; o < OUTD; ++o) acc[o] = 0.f;
#pragma unroll
        for (int j = 0; j < 8; ++j) {
            float hv = h[j];
            int i = lane * 8 + j;
#pragma unroll
            for (int o = 0; o < OUTD; ++o)
                acc[o] = fmaf(hv, Mmat[i * OUTD + o], acc[o]);
        }
#pragma unroll
        for (int o = 0; o < OUTD; ++o) {
#pragma unroll
            for (int d = 32; d; d >>= 1) acc[o] += __shfl_xor(acc[o], d, 64);
        }
        if (lane == 0) {
#pragma unroll
            for (int o = 0; o < OUTD; ++o) out[row * OUTD + o] = acc[o] + bias[o];
        }
    }
}

extern "C" void kernel_launch(void* const* d_in, const int* in_sizes, int n_in,
                              void* d_out, int out_size, void* d_ws, size_t ws_size,
                              hipStream_t stream) {
    const float* x  = (const float*)d_in[0];  // (1024, 784)
    const float* C0 = (const float*)d_in[1];  // (1, 512)
    const float* C1 = (const float*)d_in[2];  // (512, 512)
    const float* W  = (const float*)d_in[3];  // (512, 10)
    const float* b  = (const float*)d_in[4];  // (10,)
    float* M = (float*)d_ws;                  // 512*10 fp32 scratch

    compute_M<<<dim3(8), dim3(256), 0, stream>>>(C1, W, M);
    ssm_main<<<dim3(1024), dim3(128), 0, stream>>>(x, C0, M, b, (float*)d_out);
}

// Round 7
// 443.185 us; speedup vs baseline: 1.3342x; 1.2806x over previous
//
#include <hip/hip_runtime.h>
#include <math.h>

#define SEQL 784
#define HIDN 512
#define OUTD 10

typedef float v2 __attribute__((ext_vector_type(2)));

// DPP mov: lanes not selected by row_mask, or with invalid source (bound_ctrl),
// yield 0. Single-use results are foldable into v_{add,fmac}_f32_dpp.
template<int CTRL, int RM>
__device__ __forceinline__ float dpp0(float v) {
    int r = __builtin_amdgcn_update_dpp(0, __builtin_bit_cast(int, v),
                                        CTRL, RM, 0xF, true);
    return __builtin_bit_cast(float, r);
}
__device__ __forceinline__ v2 sp(float v) { v2 r; r.x = v; r.y = v; return r; }
__device__ __forceinline__ v2 vfma(v2 a, v2 b, v2 c) {
    return __builtin_elementwise_fma(a, b, c);   // -> v_pk_fma_f32
}

// M[i][o] = sum_j C1[j][i] * W[j][o]  (512 x 10): logits = h2f @ M + b.
__global__ __launch_bounds__(256) void compute_M(const float* __restrict__ C1,
                                                 const float* __restrict__ W,
                                                 float* __restrict__ M) {
    __shared__ float Ws[HIDN * OUTD];
    __shared__ float red[4][64][OUTD];
    const int lane = threadIdx.x & 63, w = threadIdx.x >> 6;
    const int i = blockIdx.x * 64 + lane;
    for (int idx = threadIdx.x; idx < HIDN * OUTD; idx += 256) Ws[idx] = W[idx];
    __syncthreads();
    float acc[OUTD];
#pragma unroll
    for (int o = 0; o < OUTD; ++o) acc[o] = 0.f;
    for (int j = w * 128; j < w * 128 + 128; ++j) {
        float cv = C1[j * HIDN + i];
#pragma unroll
        for (int o = 0; o < OUTD; ++o) acc[o] = fmaf(cv, Ws[j * OUTD + o], acc[o]);
    }
#pragma unroll
    for (int o = 0; o < OUTD; ++o) red[w][lane][o] = acc[o];
    __syncthreads();
    if (w == 0) {
#pragma unroll
        for (int o = 0; o < OUTD; ++o)
            M[i * OUTD + o] = (red[0][lane][o] + red[1][lane][o]) +
                              (red[2][lane][o] + red[3][lane][o]);
    }
}

// One wave per batch row; lane owns 8 hidden elems; layers 1/2 ride in .x/.y
// of packed fp32, with layer 2 lagging TWO steps (y0 carried in registers, no
// LDS in the loop). Per step: h <- tanh(solve((I+cA)h + du*P)) as ONE affine
// scan over (r = prefix P.h, s = solve state). Pass 2 uses the identity
// 1 - a_i + e_i == 0, so the global correction state obeys S' = a*S + zz with
// S0 = ri + si (no K1/K2 reconstruction, no Bd).
__global__ __launch_bounds__(256, 1) void ssm_main(const float* __restrict__ x,
                                                   const float* __restrict__ C0,
                                                   const float* __restrict__ Mmat,
                                                   const float* __restrict__ bias,
                                                   float* __restrict__ out) {
    const int tid = threadIdx.x;
    const int wave = tid >> 6;
    const int lane = tid & 63;
    const int row = blockIdx.x * 4 + wave;

    __shared__ float xs[4][SEQL + 3];

    const float DEL = 1.0f / 784.0f;
    for (int idx = tid; idx < 4 * SEQL; idx += 256)
        xs[idx / SEQL][idx % SEQL] = DEL * x[blockIdx.x * 4 * SEQL + idx];
    if (tid < 12) xs[tid / 3][SEQL + (tid % 3)] = 0.f;
    __syncthreads();

    // ---- per-lane constants (fp64 -> fp32, matching reference f64 A_d/B_d)
    const double cd = 1.0 / 1568.0;            // step/2
    const double F = 2.0 * 1.4426950408889634; // 2*log2(e) fold for exp2
    float P[8], Ps[8], a_[8], G2[8], mE2[8], FT[8], C0d[8];
    double apD = 0.0, bpD = 1.0;               // in-lane partial (alpha, beta)
#pragma unroll
    for (int j = 0; j < 8; ++j) {
        int i = lane * 8 + j;
        double Pd = sqrt(1.0 + 2.0 * (double)i);
        double dd = 1.0 + cd * (double)(i + 1);
        double fd = 1.0 / dd;
        double ad = (1.0 - cd * (double)i) * fd;
        double mEd = -cd * Pd * fd;
        double ed = Pd * mEd;                   // -cP^2/d ; note 1 - a + e == 0
        double Gd = (1.0 - cd * (double)(i + 1)) * fd;
        apD = ad * apD + ed;
        bpD = ad * bpD;
        P[j]   = (float)Pd;
        Ps[j]  = (float)(Pd / F);
        a_[j]  = (float)ad;
        G2[j]  = (float)(F * Gd);
        mE2[j] = (float)(F * mEd);
        FT[j]  = (float)(F * Pd * fd);
        C0d[j] = DEL * C0[i];
    }
    // ---- scan-level constants mirroring the DPP segment structure
    float ac[6], bc[6];
    {
        double al = apD, be = bpD;
        int rl = lane & 15;
#pragma unroll
        for (int L = 0; L < 4; ++L) {          // row_shr:1,2,4,8 (row-capped)
            int d = 1 << L;
            ac[L] = (float)al; bc[L] = (float)be;
            double pa = __shfl_up(al, d, 64);
            double pb = __shfl_up(be, d, 64);
            if (rl >= d) { al += be * pa; be *= pb; }
        }
        ac[4] = (float)al; bc[4] = (float)be;  // row_bcast:15 -> rows 1,3
        {
            int src = (lane & 32) + 15;
            double pa = __shfl(al, src, 64);
            double pb = __shfl(be, src, 64);
            if (lane & 16) { al += be * pa; be *= pb; }
        }
        ac[5] = (float)al; bc[5] = (float)be;  // row_bcast:31 -> rows 2,3
        {
            double pa = __shfl(al, 31, 64);
            double pb = __shfl(be, 31, 64);
            if (lane >= 32) { al += be * pa; be *= pb; }
        }
    }

    v2 h[8];
#pragma unroll
    for (int j = 0; j < 8; ++j) h[j] = sp(0.f);

    float y0_d1 = 0.f, y0_d2 = 0.f;  // y0 pipeline regs (layer-2 lag = 2)
    float u1 = xs[wave][0];          // pre-scaled by DEL

#pragma unroll 2
    for (int k = 0; k < SEQL + 2; ++k) {
        float u_next = xs[wave][k + 1];
        v2 du; du.x = u1; du.y = y0_d2;   // y0(k-2): two full iters of slack

        // ---- pass 1: per-lane local (r,s); save in_ and zz per elem
        v2 inn[8], zz[8];
        v2 r = sp(0.f), s = sp(0.f);
#pragma unroll
        for (int j = 0; j < 8; ++j) {
            v2 hj = h[j];
            v2 in_ = vfma(sp(mE2[j]), r, sp(G2[j]) * hj);
            in_ = vfma(sp(FT[j]), du, in_);          // du*P folded into w
            inn[j] = in_;
            v2 z = sp(Ps[j]) * in_;
            zz[j] = z;
            s = vfma(sp(a_[j]), s, z);
            r = vfma(sp(P[j]), hj, r);
        }

        // ---- wave affine scan via DPP (single-use, foldable)
#define LVL(CTRL, RM, L) {                                                   \
        s.x = fmaf(bc[L], dpp0<CTRL, RM>(s.x),                               \
                   fmaf(ac[L], dpp0<CTRL, RM>(r.x), s.x));                   \
        s.y = fmaf(bc[L], dpp0<CTRL, RM>(s.y),                               \
                   fmaf(ac[L], dpp0<CTRL, RM>(r.y), s.y));                   \
        r.x += dpp0<CTRL, RM>(r.x);                                          \
        r.y += dpp0<CTRL, RM>(r.y); }
        LVL(0x111, 0xF, 0)   // row_shr:1
        LVL(0x112, 0xF, 1)   // row_shr:2
        LVL(0x114, 0xF, 2)   // row_shr:4
        LVL(0x118, 0xF, 3)   // row_shr:8
        LVL(0x142, 0xA, 4)   // row_bcast:15 -> rows 1,3
        LVL(0x143, 0xC, 5)   // row_bcast:31 -> rows 2,3
#undef LVL
        v2 ri, si;           // exclusive: state entering this lane (lane0 = 0)
        ri.x = dpp0<0x138, 0xF>(r.x);  ri.y = dpp0<0x138, 0xF>(r.y);
        si.x = dpp0<0x138, 0xF>(s.x);  si.y = dpp0<0x138, 0xF>(s.y);

        // ---- pass 2: S' = a*S + zz (S0 = ri+si); yy = inn + mE2*S; tanh
        v2 S = ri + si;
        float part = 0.f;
#pragma unroll
        for (int j = 0; j < 8; ++j) {
            v2 yy = vfma(sp(mE2[j]), S, inn[j]);
            S = vfma(sp(a_[j]), S, zz[j]);
            v2 e;  e.x = __builtin_amdgcn_exp2f(yy.x);
                   e.y = __builtin_amdgcn_exp2f(yy.y);
            v2 e1 = e + sp(1.f);
            v2 rc; rc.x = __builtin_amdgcn_rcpf(e1.x);
                   rc.y = __builtin_amdgcn_rcpf(e1.y);
            v2 hn = vfma(sp(-2.f), rc, sp(1.f));
            h[j] = hn;
            part = fmaf(C0d[j], hn.x, part);
        }
        // y0 reduce: 2 iterations of slack before consumption
        part += dpp0<0x111, 0xF>(part);
        part += dpp0<0x112, 0xF>(part);
        part += dpp0<0x114, 0xF>(part);
        part += dpp0<0x118, 0xF>(part);
        part += dpp0<0x142, 0xA>(part);
        part += dpp0<0x143, 0xC>(part);
        y0_d2 = y0_d1;
        y0_d1 = __builtin_bit_cast(float,
                  __builtin_amdgcn_readlane(__builtin_bit_cast(int, part), 63));
        u1 = u_next;
    }

    // ---- epilogue: logits[row] = h2_final @ M + b (M direct from global/L2)
    float acc[OUTD];
#pragma unroll
    for (int o = 0; o < OUTD; ++o) acc[o] = 0.f;
#pragma unroll
    for (int j = 0; j < 8; ++j) {
        float hv = h[j].y;
        int i = lane * 8 + j;
#pragma unroll
        for (int o = 0; o < OUTD; ++o)
            acc[o] = fmaf(hv, Mmat[i * OUTD + o], acc[o]);
    }
#pragma unroll
    for (int o = 0; o < OUTD; ++o) {
#pragma unroll
        for (int d = 32; d; d >>= 1) acc[o] += __shfl_xor(acc[o], d, 64);
    }
    if (lane == 0) {
#pragma unroll
        for (int o = 0; o < OUTD; ++o) out[row * OUTD + o] = acc[o] + bias[o];
    }
}

extern "C" void kernel_launch(void* const* d_in, const int* in_sizes, int n_in,
                              void* d_out, int out_size, void* d_ws, size_t ws_size,
                              hipStream_t stream) {
    const float* x  = (const float*)d_in[0];  // (1024, 784)
    const float* C0 = (const float*)d_in[1];  // (1, 512)
    const float* C1 = (const float*)d_in[2];  // (512, 512)
    const float* W  = (const float*)d_in[3];  // (512, 10)
    const float* b  = (const float*)d_in[4];  // (10,)
    float* M = (float*)d_ws;                  // 512*10 fp32 scratch

    compute_M<<<dim3(8), dim3(256), 0, stream>>>(C1, W, M);
    ssm_main<<<dim3(256), dim3(256), 0, stream>>>(x, C0, M, b, (float*)d_out);
}

// Round 8
// 424.536 us; speedup vs baseline: 1.3928x; 1.0439x over previous
//
#include <hip/hip_runtime.h>
#include <math.h>

#define SEQL 784
#define HIDN 512
#define OUTD 10

typedef float v2 __attribute__((ext_vector_type(2)));

// DPP mov: lanes not selected by row_mask, or with invalid source (bound_ctrl),
// yield 0. Single-use results are foldable into v_{add,fmac}_f32_dpp.
template<int CTRL, int RM>
__device__ __forceinline__ float dpp0(float v) {
    int r = __builtin_amdgcn_update_dpp(0, __builtin_bit_cast(int, v),
                                        CTRL, RM, 0xF, true);
    return __builtin_bit_cast(float, r);
}
__device__ __forceinline__ v2 sp(float v) { v2 r; r.x = v; r.y = v; return r; }
__device__ __forceinline__ v2 vfma(v2 a, v2 b, v2 c) {
    return __builtin_elementwise_fma(a, b, c);   // -> v_pk_fma_f32
}

// M[i][o] = sum_j C1[j][i] * W[j][o]  (512 x 10): logits = h2f @ M + b.
__global__ __launch_bounds__(256) void compute_M(const float* __restrict__ C1,
                                                 const float* __restrict__ W,
                                                 float* __restrict__ M) {
    __shared__ float Ws[HIDN * OUTD];
    __shared__ float red[4][64][OUTD];
    const int lane = threadIdx.x & 63, w = threadIdx.x >> 6;
    const int i = blockIdx.x * 64 + lane;
    for (int idx = threadIdx.x; idx < HIDN * OUTD; idx += 256) Ws[idx] = W[idx];
    __syncthreads();
    float acc[OUTD];
#pragma unroll
    for (int o = 0; o < OUTD; ++o) acc[o] = 0.f;
    for (int j = w * 128; j < w * 128 + 128; ++j) {
        float cv = C1[j * HIDN + i];
#pragma unroll
        for (int o = 0; o < OUTD; ++o) acc[o] = fmaf(cv, Ws[j * OUTD + o], acc[o]);
    }
#pragma unroll
    for (int o = 0; o < OUTD; ++o) red[w][lane][o] = acc[o];
    __syncthreads();
    if (w == 0) {
#pragma unroll
        for (int o = 0; o < OUTD; ++o)
            M[i * OUTD + o] = (red[0][lane][o] + red[1][lane][o]) +
                              (red[2][lane][o] + red[3][lane][o]);
    }
}

// One wave per batch row; lane owns 8 hidden elems; layers 1/2 ride in .x/.y
// of packed fp32, with layer 2 lagging TWO steps (y0 carried in registers).
// Per step: h <- tanh(solve((I+cA)h + du*P)) as ONE affine scan over
// (r = prefix P.h, s = solve state); pass 2 uses 1 - a_i + e_i == 0 so the
// global correction obeys S' = a*S + zz with S0 = ri + si. Pass 2 is
// breadth-first so the 16 exp2 / 16 rcp (quarter-rate) stream without
// dependency bubbles; unroll-4 lets pass1(k+1) fill pass2(k) trans latency.
__global__ __launch_bounds__(256, 1) void ssm_main(const float* __restrict__ x,
                                                   const float* __restrict__ C0,
                                                   const float* __restrict__ Mmat,
                                                   const float* __restrict__ bias,
                                                   float* __restrict__ out) {
    const int tid = threadIdx.x;
    const int wave = tid >> 6;
    const int lane = tid & 63;
    const int row = blockIdx.x * 4 + wave;

    __shared__ float xs[4][SEQL + 5];

    const float DEL = 1.0f / 784.0f;
    for (int idx = tid; idx < 4 * SEQL; idx += 256)
        xs[idx / SEQL][idx % SEQL] = DEL * x[blockIdx.x * 4 * SEQL + idx];
    if (tid < 20) xs[tid / 5][SEQL + (tid % 5)] = 0.f;
    __syncthreads();

    // ---- per-lane constants (fp64 -> fp32, matching reference f64 A_d/B_d)
    const double cd = 1.0 / 1568.0;            // step/2
    const double F = 2.0 * 1.4426950408889634; // 2*log2(e) fold for exp2
    float P[8], Ps[8], a_[8], G2[8], mE2[8], FT[8], C0d[8];
    double apD = 0.0, bpD = 1.0;               // in-lane partial (alpha, beta)
#pragma unroll
    for (int j = 0; j < 8; ++j) {
        int i = lane * 8 + j;
        double Pd = sqrt(1.0 + 2.0 * (double)i);
        double dd = 1.0 + cd * (double)(i + 1);
        double fd = 1.0 / dd;
        double ad = (1.0 - cd * (double)i) * fd;
        double mEd = -cd * Pd * fd;
        double ed = Pd * mEd;                   // -cP^2/d ; note 1 - a + e == 0
        double Gd = (1.0 - cd * (double)(i + 1)) * fd;
        apD = ad * apD + ed;
        bpD = ad * bpD;
        P[j]   = (float)Pd;
        Ps[j]  = (float)(Pd / F);
        a_[j]  = (float)ad;
        G2[j]  = (float)(F * Gd);
        mE2[j] = (float)(F * mEd);
        FT[j]  = (float)(F * Pd * fd);
        C0d[j] = DEL * C0[i];
    }
    // ---- scan-level constants mirroring the DPP segment structure
    float ac[6], bc[6];
    {
        double al = apD, be = bpD;
        int rl = lane & 15;
#pragma unroll
        for (int L = 0; L < 4; ++L) {          // row_shr:1,2,4,8 (row-capped)
            int d = 1 << L;
            ac[L] = (float)al; bc[L] = (float)be;
            double pa = __shfl_up(al, d, 64);
            double pb = __shfl_up(be, d, 64);
            if (rl >= d) { al += be * pa; be *= pb; }
        }
        ac[4] = (float)al; bc[4] = (float)be;  // row_bcast:15 -> rows 1,3
        {
            int src = (lane & 32) + 15;
            double pa = __shfl(al, src, 64);
            double pb = __shfl(be, src, 64);
            if (lane & 16) { al += be * pa; be *= pb; }
        }
        ac[5] = (float)al; bc[5] = (float)be;  // row_bcast:31 -> rows 2,3
        {
            double pa = __shfl(al, 31, 64);
            double pb = __shfl(be, 31, 64);
            if (lane >= 32) { al += be * pa; be *= pb; }
        }
    }

    v2 h[8];
#pragma unroll
    for (int j = 0; j < 8; ++j) h[j] = sp(0.f);

    float y0_d1 = 0.f, y0_d2 = 0.f;  // y0 pipeline regs (layer-2 lag = 2)
    float u1 = xs[wave][0];          // pre-scaled by DEL

#pragma unroll 4
    for (int k = 0; k < SEQL + 2; ++k) {
        float u_next = xs[wave][k + 1];
        v2 du; du.x = u1; du.y = y0_d2;   // y0(k-2): two full iters of slack

        // ---- pass 1: per-lane local (r,s); save in_ and zz per elem
        v2 inn[8], zz[8];
        v2 r = sp(0.f), s = sp(0.f);
#pragma unroll
        for (int j = 0; j < 8; ++j) {
            v2 hj = h[j];
            v2 in_ = vfma(sp(mE2[j]), r, sp(G2[j]) * hj);
            in_ = vfma(sp(FT[j]), du, in_);          // du*P folded into w
            inn[j] = in_;
            v2 z = sp(Ps[j]) * in_;
            zz[j] = z;
            s = vfma(sp(a_[j]), s, z);
            r = vfma(sp(P[j]), hj, r);
        }

        // ---- wave affine scan via DPP (single-use, foldable)
#define LVL(CTRL, RM, L) {                                                   \
        s.x = fmaf(bc[L], dpp0<CTRL, RM>(s.x),                               \
                   fmaf(ac[L], dpp0<CTRL, RM>(r.x), s.x));                   \
        s.y = fmaf(bc[L], dpp0<CTRL, RM>(s.y),                               \
                   fmaf(ac[L], dpp0<CTRL, RM>(r.y), s.y));                   \
        r.x += dpp0<CTRL, RM>(r.x);                                          \
        r.y += dpp0<CTRL, RM>(r.y); }
        LVL(0x111, 0xF, 0)   // row_shr:1
        LVL(0x112, 0xF, 1)   // row_shr:2
        LVL(0x114, 0xF, 2)   // row_shr:4
        LVL(0x118, 0xF, 3)   // row_shr:8
        LVL(0x142, 0xA, 4)   // row_bcast:15 -> rows 1,3
        LVL(0x143, 0xC, 5)   // row_bcast:31 -> rows 2,3
#undef LVL
        v2 ri, si;           // exclusive: state entering this lane (lane0 = 0)
        ri.x = dpp0<0x138, 0xF>(r.x);  ri.y = dpp0<0x138, 0xF>(r.y);
        si.x = dpp0<0x138, 0xF>(s.x);  si.y = dpp0<0x138, 0xF>(s.y);

        // ---- pass 2 (breadth-first): all yy, then all exp2, then all rcp
        v2 yy[8], ee[8], rc[8];
        {
            v2 S = ri + si;
#pragma unroll
            for (int j = 0; j < 8; ++j) {
                yy[j] = vfma(sp(mE2[j]), S, inn[j]);
                S = vfma(sp(a_[j]), S, zz[j]);
            }
        }
#pragma unroll
        for (int j = 0; j < 8; ++j) {
            ee[j].x = __builtin_amdgcn_exp2f(yy[j].x);
            ee[j].y = __builtin_amdgcn_exp2f(yy[j].y);
        }
#pragma unroll
        for (int j = 0; j < 8; ++j) ee[j] = ee[j] + sp(1.f);
#pragma unroll
        for (int j = 0; j < 8; ++j) {
            rc[j].x = __builtin_amdgcn_rcpf(ee[j].x);
            rc[j].y = __builtin_amdgcn_rcpf(ee[j].y);
        }
        float part = 0.f;
#pragma unroll
        for (int j = 0; j < 8; ++j) {
            v2 hn = vfma(sp(-2.f), rc[j], sp(1.f));
            h[j] = hn;
            part = fmaf(C0d[j], hn.x, part);
        }
        // y0 reduce: 2 iterations of slack before consumption
        part += dpp0<0x111, 0xF>(part);
        part += dpp0<0x112, 0xF>(part);
        part += dpp0<0x114, 0xF>(part);
        part += dpp0<0x118, 0xF>(part);
        part += dpp0<0x142, 0xA>(part);
        part += dpp0<0x143, 0xC>(part);
        y0_d2 = y0_d1;
        y0_d1 = __builtin_bit_cast(float,
                  __builtin_amdgcn_readlane(__builtin_bit_cast(int, part), 63));
        u1 = u_next;
    }

    // ---- epilogue: logits[row] = h2_final @ M + b (M direct from global/L2)
    float acc[OUTD];
#pragma unroll
    for (int o = 0; o < OUTD; ++o) acc[o] = 0.f;
#pragma unroll
    for (int j = 0; j < 8; ++j) {
        float hv = h[j].y;
        int i = lane * 8 + j;
#pragma unroll
        for (int o = 0; o < OUTD; ++o)
            acc[o] = fmaf(hv, Mmat[i * OUTD + o], acc[o]);
    }
#pragma unroll
    for (int o = 0; o < OUTD; ++o) {
#pragma unroll
        for (int d = 32; d; d >>= 1) acc[o] += __shfl_xor(acc[o], d, 64);
    }
    if (lane == 0) {
#pragma unroll
        for (int o = 0; o < OUTD; ++o) out[row * OUTD + o] = acc[o] + bias[o];
    }
}

extern "C" void kernel_launch(void* const* d_in, const int* in_sizes, int n_in,
                              void* d_out, int out_size, void* d_ws, size_t ws_size,
                              hipStream_t stream) {
    const float* x  = (const float*)d_in[0];  // (1024, 784)
    const float* C0 = (const float*)d_in[1];  // (1, 512)
    const float* C1 = (const float*)d_in[2];  // (512, 512)
    const float* W  = (const float*)d_in[3];  // (512, 10)
    const float* b  = (const float*)d_in[4];  // (10,)
    float* M = (float*)d_ws;                  // 512*10 fp32 scratch

    compute_M<<<dim3(8), dim3(256), 0, stream>>>(C1, W, M);
    ssm_main<<<dim3(256), dim3(256), 0, stream>>>(x, C0, M, b, (float*)d_out);
}